// Round 6
// baseline (281.905 us; speedup 1.0000x reference)
//
#include <hip/hip_runtime.h>

// ===== R6: W-step halo exchange (sync-starvation test), REPEAT=3 diagnostic =====
// R5 counters: writes exact (428MB/rep), FETCH ~0, VALUBusy 37%, write rate
// 4.78 TB/s vs fill's 6.9. Theory: per-step LDS-exchange barrier convoys all
// waves; during each sync window no stores issue -> write pipe starves
// (duty ~0.67 -> 4.8 TB/s). Fix: exchange every W=4 steps. Thread carries
// K=9 center + W halo rows each side (X=17 f4), evolves halo redundantly
// (valid window shrinks 1/side/step), refills from neighbor q-groups via
// LDS every 4 steps. Barriers 50 -> 26; 4x longer store windows.
// Extra VALU: 48 vs 36 stencil-rows per 4 steps (+33%) -- still << mem time.
//
// Layout (from R4): 1024 blocks = (b, n-chunk, d-half); 256 thr = 16 d4-lanes
// x 16 q-groups; block owns T=32 rows, window SPAN=144 rows, HALO_L=56>=50.
// All s[] indices compile-time (templated period; rule #20).

namespace {

typedef float f4 __attribute__((ext_vector_type(4)));

constexpr int   REPEAT = 3;     // diagnostic replication (drop when tuned)
constexpr int   B      = 8;
constexpr int   N      = 2048;
constexpr int   D4     = 32;    // 128 floats = 32 f4 per row (global)
constexpr int   SPLITD = 2;
constexpr int   D4L    = D4 / SPLITD;   // 16 f4 lanes per block
constexpr int   STEPS  = 50;
constexpr float ALPHA  = 0.1f;
constexpr int   T      = 32;    // owned rows per block
constexpr int   QG     = 16;    // q-groups (256 thr / 16 lanes)
constexpr int   K      = 9;     // center rows per thread
constexpr int   W      = 4;     // halo depth = steps per exchange period
constexpr int   X      = K + 2 * W;     // 17 rows in registers
constexpr int   SPAN   = QG * K;        // 144 distinct window rows
constexpr int   HALO_L = (SPAN - T) / 2; // 56 >= 50
constexpr int   CHUNKS = N / T;         // 64

__device__ __forceinline__ f4 stencil(const f4 p, const f4 c, const f4 n) {
    return c + ALPHA * (p + n - 2.0f * c);
}

struct Ctx {
    int wbase;    // window row of s[0] = q*K - W
    int q, d4l, d4g, b, n0;
};

// Run w steps (w <= W), compile-time unrolled. On entry s[O..X-1-O] valid
// where O = W - w; each step shrinks validity by 1/side; center s[W..W+K-1]
// stays valid throughout. Stores owned center rows each step.
template <int w>
__device__ __forceinline__ void run_steps(f4 (&s)[X], int& k, const Ctx& cx,
                                          f4* __restrict__ out4) {
    constexpr int O = W - w;
#pragma unroll
    for (int j = 0; j < w; ++j) {
        ++k;
        constexpr int dummy = 0; (void)dummy;
        const int klo = 1 + O + j;      // constants after unroll
        const int khi = X - 2 - O - j;
        f4 prev = s[klo - 1];
#pragma unroll
        for (int i = 1 + O; i <= X - 2 - O; ++i) {  // static superset range
            if (i < klo || i > khi) continue;        // folded at compile time
            const f4 cur = s[i];
            const f4 nxt = s[i + 1];
            s[i] = stencil(prev, cur, nxt);
            prev = cur;
        }
        const int outbase = (k * B + cx.b) * N;
#pragma unroll
        for (int i = W; i < W + K; ++i) {
            const int r = cx.wbase + i - HALO_L;    // runtime, uniform
            if (r >= 0 && r < T) {
                __builtin_nontemporal_store(
                    s[i], &out4[(outbase + cx.n0 + r) * D4 + cx.d4g]);
            }
        }
    }
}

__device__ __forceinline__ void exchange(f4 (&s)[X], const Ctx& cx,
                                         f4 (*lo)[W][D4L], f4 (*hi)[W][D4L]) {
    // Post center bottom W rows and top W rows.
#pragma unroll
    for (int j = 0; j < W; ++j) {
        lo[cx.q][j][cx.d4l] = s[W + j];            // rows wbase+W..+W+3
        hi[cx.q][j][cx.d4l] = s[K + j];            // rows wbase+K..+K+3 (top 4)
    }
    asm volatile("s_waitcnt lgkmcnt(0)\n\ts_barrier" ::: "memory");
    // Refill halos from neighbors (zeros at block-window edges; creep from
    // seam row -1 over <=46 remaining steps stays < HALO_L=56).
#pragma unroll
    for (int j = 0; j < W; ++j) {
        s[j]         = (cx.q > 0)      ? hi[cx.q - 1][j][cx.d4l] : (f4)(0.f);
        s[W + K + j] = (cx.q < QG - 1) ? lo[cx.q + 1][j][cx.d4l] : (f4)(0.f);
    }
    // Reads drained before anyone re-posts (next exchange is >=2 steps away,
    // but a fast thread must not overwrite a board a slow thread still
    // hasn't read): barrier after reads.
    asm volatile("s_barrier" ::: "memory");
}

__global__ __launch_bounds__(QG * D4L, 4) void diffusion_halo(
        const f4* __restrict__ in4, f4* __restrict__ out4) {
    const int tid = threadIdx.x;
    Ctx cx;
    cx.d4l = tid & (D4L - 1);
    cx.q   = tid >> 4;

    const int bid = blockIdx.x;
    const int dh  = bid & (SPLITD - 1);
    const int c   = (bid >> 1) & (CHUNKS - 1);
    cx.b   = bid >> 7;
    cx.n0  = c * T;
    cx.d4g = dh * D4L + cx.d4l;
    cx.wbase = cx.q * K - W;

    __shared__ f4 lo[QG][W][D4L];   // 16 KB
    __shared__ f4 hi[QG][W][D4L];   // 16 KB

    for (int rep = 0; rep < REPEAT; ++rep) {
        f4 s[X];
        // Load all X rows with wraparound (all real rows -> valid at t=0).
#pragma unroll
        for (int i = 0; i < X; ++i) {
            const int ng = (cx.n0 + cx.wbase + i - HALO_L + 2 * N) & (N - 1);
            s[i] = in4[(cx.b * N + ng) * D4 + cx.d4g];
        }

        // out[0]: owned center rows.
#pragma unroll
        for (int i = W; i < W + K; ++i) {
            const int r = cx.wbase + i - HALO_L;
            if (r >= 0 && r < T) {
                __builtin_nontemporal_store(
                    s[i], &out4[(cx.b * N + cx.n0 + r) * D4 + cx.d4g]);
            }
        }

        int k = 0;
        // 12 full periods of 4 steps + 1 period of 2 steps = 50.
        for (int p = 0; p < STEPS / W; ++p) {
            if (p > 0) exchange(s, cx, lo, hi);
            run_steps<W>(s, k, cx, out4);
        }
        exchange(s, cx, lo, hi);
        run_steps<STEPS - (STEPS / W) * W>(s, k, cx, out4);
    }
}

}  // namespace

extern "C" void kernel_launch(void* const* d_in, const int* in_sizes, int n_in,
                              void* d_out, int out_size, void* d_ws, size_t ws_size,
                              hipStream_t stream) {
    const f4* in4  = reinterpret_cast<const f4*>(d_in[0]);
    f4*       out4 = reinterpret_cast<f4*>(d_out);

    dim3 grid(B * CHUNKS * SPLITD);  // 1024 blocks -> 4 per CU
    dim3 block(QG * D4L);            // 256 threads
    diffusion_halo<<<grid, block, 0, stream>>>(in4, out4);
}

// Round 7
// 265.991 us; speedup vs baseline: 1.0598x; 1.0598x over previous
//
#include <hip/hip_runtime.h>

// ===== R7: store-load balancing across waves (skew-collapse test), REPEAT=3 =====
// R5/R6 analysis: per step per CU, 32KB stores issue at fair-share ~27GB/s
// (1.16us) + ~0.6us barrier dead window = 1.8us step. Dead window = wave
// skew: owned rows (q6..q9) store only from waves 1-2; those waves are
// store-throttled while waves 0,3 idle at the barrier. Fix: permute tid->q
// so each wave holds exactly ONE storing q-group (wave w: q=6+w) + three
// halo-only groups. Equal throttling -> equal arrival -> skew ~0 ->
// step ~1.35us, write duty 64%->87%.
// Everything else = R5 exactly (K=9, per-step exchange, 1 barrier/step,
// nontemporal stores, REPEAT=3 diagnostic for counter visibility).

namespace {

typedef float f4 __attribute__((ext_vector_type(4)));

constexpr int   REPEAT = 3;     // diagnostic replication (drop when tuned)
constexpr int   B      = 8;
constexpr int   N      = 2048;
constexpr int   D4     = 32;    // 128 floats = 32 f4 per row (global)
constexpr int   SPLITD = 2;
constexpr int   D4L    = D4 / SPLITD;   // 16 f4 lanes per block
constexpr int   STEPS  = 50;
constexpr float ALPHA  = 0.1f;
constexpr int   T      = 32;    // owned rows per block
constexpr int   QG     = 16;    // q-groups (256 thr / 16 lanes)
constexpr int   K      = 9;     // rows per thread
constexpr int   R      = QG * K;        // 144 staged rows
constexpr int   HALO_L = (R - T) / 2;   // 56 >= 50
constexpr int   CHUNKS = N / T;         // 64

__device__ __forceinline__ f4 stencil(const f4 p, const f4 c, const f4 n) {
    return c + ALPHA * (p + n - 2.0f * c);
}

// Wave w holds q-groups {6+w, ...three halo-only groups...}:
//   wave0: {6, 0, 1, 2}   wave1: {7, 3, 4, 5}
//   wave2: {8,10,11,12}   wave3: {9,13,14,15}
// Owned window rows are [56,88): q6->7 rows, q7->9, q8->9, q9->7, so every
// wave stores 7-9 rows/step (was: waves 1,2 store 16 each; waves 0,3 zero).
__device__ __forceinline__ int q_of(int tid) {
    const int j    = tid >> 4;     // 16-lane group index 0..15
    const int wave = j >> 2;
    const int slot = j & 3;
    return (slot == 0) ? (6 + wave)
                       : ((wave < 2) ? (wave * 3 + slot - 1)
                                     : (10 + (wave - 2) * 3 + slot - 1));
}

__global__ __launch_bounds__(QG * D4L, 4) void diffusion_halo(
        const f4* __restrict__ in4, f4* __restrict__ out4) {
    const int tid = threadIdx.x;
    const int d4l = tid & (D4L - 1);  // f4 lane within this d-half
    const int q   = q_of(tid);        // logical row-group 0..15 (permuted)

    const int bid = blockIdx.x;
    const int dh  = bid & (SPLITD - 1);
    const int c   = (bid >> 1) & (CHUNKS - 1);
    const int b   = bid >> 7;
    const int n0  = c * T;
    const int d4g = dh * D4L + d4l;

    // Double-buffered boundary board (indexed by LOGICAL q): 1 barrier/step.
    __shared__ f4 lo[2][QG][D4L];
    __shared__ f4 hi[2][QG][D4L];

    const int rbase = q * K;

    for (int rep = 0; rep < REPEAT; ++rep) {
        f4 s[K];
        // Load K rows with wraparound: ng = (n0 + r - HALO_L) mod N.
#pragma unroll
        for (int i = 0; i < K; ++i) {
            const int ng = (n0 + rbase + i + (N - HALO_L)) & (N - 1);
            s[i] = in4[(b * N + ng) * D4 + d4g];
        }

        // out[0] = initial state (owned rows only)
#pragma unroll
        for (int i = 0; i < K; ++i) {
            const int r = rbase + i;
            if (r >= HALO_L && r < HALO_L + T) {
                __builtin_nontemporal_store(
                    s[i], &out4[(b * N + (n0 + r - HALO_L)) * D4 + d4g]);
            }
        }

        for (int k = 1; k <= STEPS; ++k) {
            const int buf = k & 1;
            // Publish old boundary rows of this group.
            lo[buf][q][d4l] = s[0];
            hi[buf][q][d4l] = s[K - 1];
            // LDS ordering only — stores stay in flight across barrier.
            asm volatile("s_waitcnt lgkmcnt(0)" ::: "memory");
            __builtin_amdgcn_s_barrier();
            const f4 bl = (q > 0)      ? hi[buf][q - 1][d4l] : (f4)(0.f);
            const f4 bh = (q < QG - 1) ? lo[buf][q + 1][d4l] : (f4)(0.f);
            // No second barrier: next iter writes buf^1; reuse of buf two
            // steps later is fenced by intervening lgkmcnt(0)+barrier.

            // In-register carry-chain stencil; store owned rows as made.
            const int outbase = (k * B + b) * N;
            f4 prev = bl;
#pragma unroll
            for (int i = 0; i < K; ++i) {
                const f4 cur = s[i];
                f4 nxt = bh;
                if (i + 1 < K) nxt = s[i + 1];
                s[i] = stencil(prev, cur, nxt);
                prev = cur;
                const int r = rbase + i;
                if (r >= HALO_L && r < HALO_L + T) {
                    __builtin_nontemporal_store(
                        s[i],
                        &out4[(outbase + (n0 + r - HALO_L)) * D4 + d4g]);
                }
            }
        }
    }
}

}  // namespace

extern "C" void kernel_launch(void* const* d_in, const int* in_sizes, int n_in,
                              void* d_out, int out_size, void* d_ws, size_t ws_size,
                              hipStream_t stream) {
    const f4* in4  = reinterpret_cast<const f4*>(d_in[0]);
    f4*       out4 = reinterpret_cast<f4*>(d_out);

    dim3 grid(B * CHUNKS * SPLITD);  // 1024 blocks -> 4 per CU
    dim3 block(QG * D4L);            // 256 threads
    diffusion_halo<<<grid, block, 0, stream>>>(in4, out4);
}